// Round 8
// baseline (288.365 us; speedup 1.0000x reference)
//
#include <hip/hip_runtime.h>
#include <hip/hip_bf16.h>

#define B_ROWS 65536
#define KNUM 20
#define ZROW 5000   // extra all-zero row appended to ekb (masked-gather target)

typedef short  bfrag8 __attribute__((ext_vector_type(8)));  // 8 bf16 (4 VGPRs)
typedef float  facc4  __attribute__((ext_vector_type(4)));  // 4 fp32

__device__ __forceinline__ unsigned short f2bf(float f) {
    union { float f; unsigned u; } x; x.f = f;
    unsigned r = (x.u + 0x7FFFu + ((x.u >> 16) & 1u)) >> 16;   // RNE
    return (unsigned short)r;
}
__device__ __forceinline__ float bf2f(unsigned s) {
    union { unsigned u; float f; } x; x.u = s << 16; return x.f;
}

// ---------------------------------------------------------------------------
// Prepack: weights -> bf16 transposed [N][K]; emb_k -> bf16 copy + zero row.
// ROUND-8: table back to bf16 (ekb): the standalone gather kernel is
// L2-BW-bound (1.0 GB L2 reads with f32 = ~29 us floor); bf16 halves that.
// (r3's f32 table was null only because the FUSED gather was latency-bound.)
//   WT1: 114688 ush | WT2: 32768 | WT3: 8192 | ekb: 320064 ush (5001 rows)
// ---------------------------------------------------------------------------
__global__ __launch_bounds__(256) void prepack(
    const float* __restrict__ W1, const float* __restrict__ W2,
    const float* __restrict__ W3, const float* __restrict__ ek,
    unsigned short* __restrict__ WT1, unsigned short* __restrict__ WT2,
    unsigned short* __restrict__ WT3, unsigned short* __restrict__ ekb)
{
    const int i = blockIdx.x * 256 + threadIdx.x;
    if (i < 114688) {                 // WT1[n*448+k] = bf16(W1[k*256+n])
        const int n = i / 448, k = i % 448;
        WT1[i] = f2bf(W1[k * 256 + n]);
    } else if (i < 147456) {          // WT2[n*256+k] = bf16(W2[k*128+n])
        const int j = i - 114688;
        WT2[j] = f2bf(W2[(j & 255) * 128 + (j >> 8)]);
    } else if (i < 155648) {          // WT3[n*128+k] = bf16(W3[k*64+n])
        const int j = i - 147456;
        WT3[j] = f2bf(W3[(j & 127) * 64 + (j >> 7)]);
    } else if (i < 475712) {          // ekb = bf16 ek + zero row at ZROW
        const int j = i - 155648;
        ekb[j] = (j < 320000) ? f2bf(ek[j]) : (unsigned short)0;
    }
}

// ---------------------------------------------------------------------------
// Standalone masked-mean gather -> Xm[65536][192] bf16 (r7 structure: no LDS,
// no barriers, waves free-run; 2048 blocks x 256 thr, 8 rows/wave).
// r8: bf16 table -> 128B/wave-load (was 256B), halving the L2-read floor.
// WRITE_SIZE ~25.2 MB is BY DESIGN (Xm); spill tripwire is write >> 26 MB.
// ---------------------------------------------------------------------------
__global__ __launch_bounds__(256, 6) void kdmlp_gather(
    const int* __restrict__ pk, const int* __restrict__ tk,
    const int* __restrict__ ik, const int* __restrict__ vp,
    const int* __restrict__ vt, const int* __restrict__ vi,
    const unsigned short* __restrict__ ekb, unsigned short* __restrict__ Xm)
{
    const int lane = threadIdx.x & 63;
    const int gw   = blockIdx.x * 4 + (threadIdx.x >> 6);   // global wave 0..8191
    const int r0   = gw * 8;

    // lane->packed-index mapping: 0..19 pk | 20..39 tk | 40..59 ik | 60..63 dup
    const int* basep = (lane < 20) ? pk : (lane < 40) ? tk : ik;
    const int  loff  = (lane < 20) ? lane
                     : (lane < 40) ? lane - 20
                     : (lane < 60) ? lane - 40 : 19;

    int idxv[8];
    #pragma unroll
    for (int lr = 0; lr < 8; ++lr)
        idxv[lr] = basep[(size_t)(r0 + lr) * KNUM + loff];

    #pragma unroll
    for (int lr = 0; lr < 8; ++lr) {
        const int r = r0 + lr;
        const int vld0 = __builtin_amdgcn_readfirstlane(vp[r]);
        const int vld1 = __builtin_amdgcn_readfirstlane(vt[r]);
        const int vld2 = __builtin_amdgcn_readfirstlane(vi[r]);
        #pragma unroll
        for (int s = 0; s < 3; ++s) {
            const int vld = (s == 0) ? vld0 : (s == 1) ? vld1 : vld2;
            float acc0 = 0.f, acc1 = 0.f;       // 2 chains: halve add latency
            #pragma unroll
            for (int j = 0; j < KNUM; j += 2) {
                int k0 = __builtin_amdgcn_readlane(idxv[lr], s * KNUM + j);
                int k1 = __builtin_amdgcn_readlane(idxv[lr], s * KNUM + j + 1);
                k0 = (j     < vld) ? k0 : ZROW;                 // s_cselect
                k1 = (j + 1 < vld) ? k1 : ZROW;
                acc0 += bf2f(ekb[(size_t)k0 * 64 + lane]);      // saddr 2B load
                acc1 += bf2f(ekb[(size_t)k1 * 64 + lane]);
            }
            const float acc  = acc0 + acc1;
            const float mean = (vld > 0) ? acc / (float)vld : 0.f;
            Xm[(size_t)r * 192 + s * 64 + lane] = f2bf(mean);
        }
    }
}

// ---------------------------------------------------------------------------
// MLP kernel, r7 structure with ROUND-8 persistence: grid 512, each block
// processes TWO 64-row tiles serially. Halves WT1/2/3 L2 re-streams
// (229 -> 115 MB) and per-block fixed cost; 2 blocks/CU unchanged.
// Inter-tile hazard: tile t+1 phase-0 writes Xs[0,58368) -- disjoint from
// tmp[58368,..) reads after tile t's final barrier; all H1s/H2s reads
// completed before that barrier.
// LDS 59392 B: Xs[64][456] -> H1s[64][264] @0, H2s[64][136] @33792,
//              tmp[64][4] @58368.
// ---------------------------------------------------------------------------
__global__ __launch_bounds__(512, 4) void kdmlp_mlp(
    const int* __restrict__ user, const int* __restrict__ item,
    const float* __restrict__ eu, const float* __restrict__ ei,
    const unsigned short* __restrict__ Xm,
    const unsigned short* __restrict__ WT1, const unsigned short* __restrict__ WT2,
    const unsigned short* __restrict__ WT3,
    const float* __restrict__ b1, const float* __restrict__ b2,
    const float* __restrict__ b3, const float* __restrict__ Wp,
    const float* __restrict__ bp, float* __restrict__ out)
{
    __shared__ char smem[59392];
    unsigned short* Xs  = (unsigned short*)smem;            // stride 456
    unsigned short* H1s = (unsigned short*)smem;            // stride 264
    unsigned short* H2s = (unsigned short*)(smem + 33792);  // stride 136
    float (*tmp)[4]     = (float(*)[4])(smem + 58368);

    const int tid  = threadIdx.x;
    const int lane = tid & 63;
    const int wid  = tid >> 6;          // 0..7
    const int lm   = lane & 15;
    const int quad = lane >> 4;

    #pragma unroll 1
    for (int tt = 0; tt < 2; ++tt) {
        const int m0 = (blockIdx.x * 2 + tt) * 64;

        // ---- early issue: GEMM1 B (ks=0); completes during phase 0 ----
        bfrag8 g1b0[2], g1b1[2];
        #pragma unroll
        for (int nt = 0; nt < 2; ++nt)
            g1b0[nt] = *(const bfrag8*)(WT1 + (size_t)(wid * 32 + nt * 16 + lm) * 448
                                            + quad * 8);

        // ============= phase 0: assemble Xs from eu/ei/Xm =============
        #pragma unroll
        for (int lr = 0; lr < 8; ++lr) {
            const int rl = wid * 8 + lr;    // local row 0..63
            const int r  = __builtin_amdgcn_readfirstlane(m0 + rl);
            const int u   = __builtin_amdgcn_readfirstlane(user[r]);
            const int itm = __builtin_amdgcn_readfirstlane(item[r]);
            float2 a = *(const float2*)(eu + (size_t)u   * 128 + 2 * lane);
            float2 b = *(const float2*)(ei + (size_t)itm * 128 + 2 * lane);
            ushort2 pa; pa.x = f2bf(a.x); pa.y = f2bf(a.y);
            ushort2 pb; pb.x = f2bf(b.x); pb.y = f2bf(b.y);
            *(ushort2*)(Xs + rl * 456 + 2 * lane)       = pa;
            *(ushort2*)(Xs + rl * 456 + 128 + 2 * lane) = pb;
            if (lane < 24)                  // 24 x 16B = 192 ush = the 3 means
                *(bfrag8*)(Xs + rl * 456 + 256 + lane * 8) =
                    *(const bfrag8*)(Xm + (size_t)(m0 + rl) * 192 + lane * 8);
        }
        __syncthreads();                    // Xs complete; g1b0 resident

        // ============= GEMM1: [64,448] @ W1 -> H1 [64,256] =============
        facc4 acc1[4][2];
        #pragma unroll
        for (int mt = 0; mt < 4; ++mt)
            #pragma unroll
            for (int nt = 0; nt < 2; ++nt)
                acc1[mt][nt] = (facc4){0.f, 0.f, 0.f, 0.f};

        #pragma unroll
        for (int kp = 0; kp < 7; ++kp) {            // K = 448 = 7 * (2*32)
            const int ksA = 2 * kp, ksB = 2 * kp + 1;
            #pragma unroll
            for (int nt = 0; nt < 2; ++nt)          // prefetch ksB
                g1b1[nt] = *(const bfrag8*)(WT1 + (size_t)(wid * 32 + nt * 16 + lm) * 448
                                                + ksB * 32 + quad * 8);
            bfrag8 af[4];
            #pragma unroll
            for (int mt = 0; mt < 4; ++mt)
                af[mt] = *(const bfrag8*)(Xs + (mt * 16 + lm) * 456 + ksA * 32 + quad * 8);
            #pragma unroll
            for (int mt = 0; mt < 4; ++mt)
                #pragma unroll
                for (int nt = 0; nt < 2; ++nt)
                    acc1[mt][nt] = __builtin_amdgcn_mfma_f32_16x16x32_bf16(
                        af[mt], g1b0[nt], acc1[mt][nt], 0, 0, 0);
            if (kp < 6) {
                #pragma unroll
                for (int nt = 0; nt < 2; ++nt)      // prefetch next pair's ksA
                    g1b0[nt] = *(const bfrag8*)(WT1 + (size_t)(wid * 32 + nt * 16 + lm) * 448
                                                    + (ksB + 1) * 32 + quad * 8);
            }
            #pragma unroll
            for (int mt = 0; mt < 4; ++mt)
                af[mt] = *(const bfrag8*)(Xs + (mt * 16 + lm) * 456 + ksB * 32 + quad * 8);
            #pragma unroll
            for (int mt = 0; mt < 4; ++mt)
                #pragma unroll
                for (int nt = 0; nt < 2; ++nt)
                    acc1[mt][nt] = __builtin_amdgcn_mfma_f32_16x16x32_bf16(
                        af[mt], g1b1[nt], acc1[mt][nt], 0, 0, 0);
        }

        // ---- early issue: GEMM2 B (ks=0) ----
        const int colw = wid * 16 + lm;             // this wave's col in GEMM2/H2
        bfrag8 g2b0 = *(const bfrag8*)(WT2 + (size_t)colw * 256 + quad * 8);
        bfrag8 g2b1;

        __syncthreads();                            // all Xs reads done

        // epilogue 1 -> H1s (C/D: col=lane&15 base, row=quad*4+reg)
        #pragma unroll
        for (int nt = 0; nt < 2; ++nt) {
            const int col = wid * 32 + nt * 16 + lm;
            const float bias = b1[col];
            #pragma unroll
            for (int mt = 0; mt < 4; ++mt)
                #pragma unroll
                for (int i = 0; i < 4; ++i) {
                    const int row = mt * 16 + quad * 4 + i;
                    H1s[row * 264 + col] = f2bf(fmaxf(acc1[mt][nt][i] + bias, 0.f));
                }
        }
        __syncthreads();

        // ============= GEMM2: [64,256] @ W2 -> H2 [64,128] =============
        facc4 acc2[4];
        #pragma unroll
        for (int mt = 0; mt < 4; ++mt) acc2[mt] = (facc4){0.f, 0.f, 0.f, 0.f};

        #pragma unroll
        for (int kp = 0; kp < 4; ++kp) {            // K = 256 = 4 * (2*32)
            const int ksA = 2 * kp, ksB = 2 * kp + 1;
            g2b1 = *(const bfrag8*)(WT2 + (size_t)colw * 256 + ksB * 32 + quad * 8);
            bfrag8 af[4];
            #pragma unroll
            for (int mt = 0; mt < 4; ++mt)
                af[mt] = *(const bfrag8*)(H1s + (mt * 16 + lm) * 264 + ksA * 32 + quad * 8);
            #pragma unroll
            for (int mt = 0; mt < 4; ++mt)
                acc2[mt] = __builtin_amdgcn_mfma_f32_16x16x32_bf16(af[mt], g2b0, acc2[mt], 0, 0, 0);
            if (kp < 3)
                g2b0 = *(const bfrag8*)(WT2 + (size_t)colw * 256 + (ksB + 1) * 32 + quad * 8);
            #pragma unroll
            for (int mt = 0; mt < 4; ++mt)
                af[mt] = *(const bfrag8*)(H1s + (mt * 16 + lm) * 264 + ksB * 32 + quad * 8);
            #pragma unroll
            for (int mt = 0; mt < 4; ++mt)
                acc2[mt] = __builtin_amdgcn_mfma_f32_16x16x32_bf16(af[mt], g2b1, acc2[mt], 0, 0, 0);
        }

        // ---- early issue: GEMM3 B (all 4 ks) ----
        const int w3   = wid & 3;
        const int mgrp = wid >> 2;
        const int col3 = w3 * 16 + lm;
        bfrag8 g3b[4];
        #pragma unroll
        for (int ks = 0; ks < 4; ++ks)
            g3b[ks] = *(const bfrag8*)(WT3 + (size_t)col3 * 128 + ks * 32 + quad * 8);

        // epilogue 2 -> H2s (disjoint from H1s reads; barrier only after)
        {
            const float bias = b2[colw];
            #pragma unroll
            for (int mt = 0; mt < 4; ++mt)
                #pragma unroll
                for (int i = 0; i < 4; ++i) {
                    const int row = mt * 16 + quad * 4 + i;
                    H2s[row * 136 + colw] = f2bf(fmaxf(acc2[mt][i] + bias, 0.f));
                }
        }
        __syncthreads();

        // ====== GEMM3: [64,128] @ W3 -> relu -> dot Wp, fused reduce ======
        {
            facc4 acc3[2];
            #pragma unroll
            for (int mtl = 0; mtl < 2; ++mtl) acc3[mtl] = (facc4){0.f, 0.f, 0.f, 0.f};

            #pragma unroll
            for (int ks = 0; ks < 4; ++ks) {        // K = 128 = 4 * 32
                bfrag8 af[2];
                #pragma unroll
                for (int mtl = 0; mtl < 2; ++mtl)
                    af[mtl] = *(const bfrag8*)(H2s + (mgrp * 32 + mtl * 16 + lm) * 136
                                                   + ks * 32 + quad * 8);
                #pragma unroll
                for (int mtl = 0; mtl < 2; ++mtl)
                    acc3[mtl] = __builtin_amdgcn_mfma_f32_16x16x32_bf16(
                        af[mtl], g3b[ks], acc3[mtl], 0, 0, 0);
            }
            const float bias = b3[col3];
            const float wpv  = Wp[col3];
            #pragma unroll
            for (int mtl = 0; mtl < 2; ++mtl)
                #pragma unroll
                for (int i = 0; i < 4; ++i) {
                    float p = fmaxf(acc3[mtl][i] + bias, 0.f) * wpv;
                    p += __shfl_xor(p, 1);
                    p += __shfl_xor(p, 2);
                    p += __shfl_xor(p, 4);
                    p += __shfl_xor(p, 8);          // sum over the 16 cols (lm)
                    if (lm == 0) tmp[mgrp * 32 + mtl * 16 + quad * 4 + i][w3] = p;
                }
        }
        __syncthreads();

        if (tid < 64)
            out[m0 + tid] = tmp[tid][0] + tmp[tid][1] + tmp[tid][2] + tmp[tid][3]
                          + bp[0];
        // next tile's Xs writes [0,58368) are disjoint from tmp reads [58368,..)
    }
}

// ---------------------------------------------------------------------------
extern "C" void kernel_launch(void* const* d_in, const int* in_sizes, int n_in,
                              void* d_out, int out_size, void* d_ws, size_t ws_size,
                              hipStream_t stream) {
    (void)in_sizes; (void)n_in; (void)out_size; (void)ws_size;

    const int*   user = (const int*)d_in[0];
    const int*   item = (const int*)d_in[1];
    const int*   pk   = (const int*)d_in[2];
    const int*   tk   = (const int*)d_in[3];
    const int*   ik   = (const int*)d_in[4];
    const int*   vp   = (const int*)d_in[5];
    const int*   vt   = (const int*)d_in[6];
    const int*   vi   = (const int*)d_in[7];
    const float* eu   = (const float*)d_in[8];
    const float* ei   = (const float*)d_in[9];
    const float* ek   = (const float*)d_in[10];
    const float* W1   = (const float*)d_in[11];
    const float* b1   = (const float*)d_in[12];
    const float* W2   = (const float*)d_in[13];
    const float* b2   = (const float*)d_in[14];
    const float* W3   = (const float*)d_in[15];
    const float* b3   = (const float*)d_in[16];
    const float* Wp   = (const float*)d_in[17];
    const float* bp   = (const float*)d_in[18];
    float* out = (float*)d_out;

    // ws layout (~26 MB):
    //   WT1 114688 ush | WT2 32768 | WT3 8192 | ekb 320064 ush | Xm 65536x192 ush
    unsigned short* WT1 = (unsigned short*)d_ws;
    unsigned short* WT2 = WT1 + 114688;
    unsigned short* WT3 = WT2 + 32768;
    unsigned short* ekb = WT3 + 8192;
    unsigned short* Xm  = ekb + 320064;   // 16B-aligned (475712 ush from base)

    prepack<<<1859, 256, 0, stream>>>(W1, W2, W3, ek, WT1, WT2, WT3, ekb);

    kdmlp_gather<<<2048, 256, 0, stream>>>(pk, tk, ik, vp, vt, vi, ekb, Xm);

    kdmlp_mlp<<<512, 512, 0, stream>>>(
        user, item, eu, ei, Xm, WT1, WT2, WT3, b1, b2, b3, Wp, bp, out);
}

// Round 9
// 240.957 us; speedup vs baseline: 1.1967x; 1.1967x over previous
//
#include <hip/hip_runtime.h>
#include <hip/hip_bf16.h>

#define B_ROWS 65536
#define KNUM 20
#define ZROW 5000   // extra all-zero row appended to ekb (masked-gather target)

typedef short  bfrag8 __attribute__((ext_vector_type(8)));  // 8 bf16 (4 VGPRs)
typedef float  facc4  __attribute__((ext_vector_type(4)));  // 4 fp32

__device__ __forceinline__ unsigned short f2bf(float f) {
    union { float f; unsigned u; } x; x.f = f;
    unsigned r = (x.u + 0x7FFFu + ((x.u >> 16) & 1u)) >> 16;   // RNE
    return (unsigned short)r;
}
__device__ __forceinline__ float bf2f(unsigned s) {
    union { unsigned u; float f; } x; x.u = s << 16; return x.f;
}

// ---------------------------------------------------------------------------
// Prepack: weights -> bf16 transposed [N][K]; emb_k -> bf16 copy + zero row.
//   WT1: 114688 ush | WT2: 32768 | WT3: 8192 | ekb: 320064 ush (5001 rows)
// ---------------------------------------------------------------------------
__global__ __launch_bounds__(256) void prepack(
    const float* __restrict__ W1, const float* __restrict__ W2,
    const float* __restrict__ W3, const float* __restrict__ ek,
    unsigned short* __restrict__ WT1, unsigned short* __restrict__ WT2,
    unsigned short* __restrict__ WT3, unsigned short* __restrict__ ekb)
{
    const int i = blockIdx.x * 256 + threadIdx.x;
    if (i < 114688) {                 // WT1[n*448+k] = bf16(W1[k*256+n])
        const int n = i / 448, k = i % 448;
        WT1[i] = f2bf(W1[k * 256 + n]);
    } else if (i < 147456) {          // WT2[n*256+k] = bf16(W2[k*128+n])
        const int j = i - 114688;
        WT2[j] = f2bf(W2[(j & 255) * 128 + (j >> 8)]);
    } else if (i < 155648) {          // WT3[n*128+k] = bf16(W3[k*64+n])
        const int j = i - 147456;
        WT3[j] = f2bf(W3[(j & 127) * 64 + (j >> 7)]);
    } else if (i < 475712) {          // ekb = bf16 ek + zero row at ZROW
        const int j = i - 155648;
        ekb[j] = (j < 320000) ? f2bf(ek[j]) : (unsigned short)0;
    }
}

// ---------------------------------------------------------------------------
// Standalone masked-mean gather -> Xm[65536][192] bf16 (r7 structure: no LDS,
// no barriers, waves free-run; 2048 blocks x 256 thr, 8 rows/wave; bf16 table
// = r8, kept: 128B/wave-load halves the L2-read floor, measured ~neutral-to-
// slightly-positive vs f32).  WRITE_SIZE ~25.2 MB is BY DESIGN (Xm).
// ---------------------------------------------------------------------------
__global__ __launch_bounds__(256, 6) void kdmlp_gather(
    const int* __restrict__ pk, const int* __restrict__ tk,
    const int* __restrict__ ik, const int* __restrict__ vp,
    const int* __restrict__ vt, const int* __restrict__ vi,
    const unsigned short* __restrict__ ekb, unsigned short* __restrict__ Xm)
{
    const int lane = threadIdx.x & 63;
    const int gw   = blockIdx.x * 4 + (threadIdx.x >> 6);   // global wave 0..8191
    const int r0   = gw * 8;

    // lane->packed-index mapping: 0..19 pk | 20..39 tk | 40..59 ik | 60..63 dup
    const int* basep = (lane < 20) ? pk : (lane < 40) ? tk : ik;
    const int  loff  = (lane < 20) ? lane
                     : (lane < 40) ? lane - 20
                     : (lane < 60) ? lane - 40 : 19;

    int idxv[8];
    #pragma unroll
    for (int lr = 0; lr < 8; ++lr)
        idxv[lr] = basep[(size_t)(r0 + lr) * KNUM + loff];

    #pragma unroll
    for (int lr = 0; lr < 8; ++lr) {
        const int r = r0 + lr;
        const int vld0 = __builtin_amdgcn_readfirstlane(vp[r]);
        const int vld1 = __builtin_amdgcn_readfirstlane(vt[r]);
        const int vld2 = __builtin_amdgcn_readfirstlane(vi[r]);
        #pragma unroll
        for (int s = 0; s < 3; ++s) {
            const int vld = (s == 0) ? vld0 : (s == 1) ? vld1 : vld2;
            float acc0 = 0.f, acc1 = 0.f;       // 2 chains: halve add latency
            #pragma unroll
            for (int j = 0; j < KNUM; j += 2) {
                int k0 = __builtin_amdgcn_readlane(idxv[lr], s * KNUM + j);
                int k1 = __builtin_amdgcn_readlane(idxv[lr], s * KNUM + j + 1);
                k0 = (j     < vld) ? k0 : ZROW;                 // s_cselect
                k1 = (j + 1 < vld) ? k1 : ZROW;
                acc0 += bf2f(ekb[(size_t)k0 * 64 + lane]);      // saddr 2B load
                acc1 += bf2f(ekb[(size_t)k1 * 64 + lane]);
            }
            const float acc  = acc0 + acc1;
            const float mean = (vld > 0) ? acc / (float)vld : 0.f;
            Xm[(size_t)r * 192 + s * 64 + lane] = f2bf(mean);
        }
    }
}

// ---------------------------------------------------------------------------
// MLP kernel: r7 structure VERBATIM (69.5 us, VGPR 52, zero scratch).
// r8's persistent 2-tile loop REVERTED: wrapping this body in any enclosing
// loop spills (~225 B/thread scratch, WRITE 118 MB, dur 122 us). The body is
// at its register budget edge -- do not enclose it in control structures.
// One block = 64 rows, 512 thr = 8 waves, 2 blk/CU, grid 1024.
// LDS 59392 B: Xs[64][456] -> H1s[64][264] @0, H2s[64][136] @33792,
//              tmp[64][4] @58368.
// ---------------------------------------------------------------------------
__global__ __launch_bounds__(512, 4) void kdmlp_mlp(
    const int* __restrict__ user, const int* __restrict__ item,
    const float* __restrict__ eu, const float* __restrict__ ei,
    const unsigned short* __restrict__ Xm,
    const unsigned short* __restrict__ WT1, const unsigned short* __restrict__ WT2,
    const unsigned short* __restrict__ WT3,
    const float* __restrict__ b1, const float* __restrict__ b2,
    const float* __restrict__ b3, const float* __restrict__ Wp,
    const float* __restrict__ bp, float* __restrict__ out)
{
    __shared__ char smem[59392];
    unsigned short* Xs  = (unsigned short*)smem;            // stride 456
    unsigned short* H1s = (unsigned short*)smem;            // stride 264
    unsigned short* H2s = (unsigned short*)(smem + 33792);  // stride 136
    float (*tmp)[4]     = (float(*)[4])(smem + 58368);

    const int tid  = threadIdx.x;
    const int lane = tid & 63;
    const int wid  = tid >> 6;          // 0..7
    const int lm   = lane & 15;
    const int quad = lane >> 4;
    const int m0   = blockIdx.x * 64;

    // ---- early issue: GEMM1 B (ks=0); completes during phase 0 ----
    bfrag8 g1b0[2], g1b1[2];
    #pragma unroll
    for (int nt = 0; nt < 2; ++nt)
        g1b0[nt] = *(const bfrag8*)(WT1 + (size_t)(wid * 32 + nt * 16 + lm) * 448
                                        + quad * 8);

    // ================= phase 0: assemble Xs from eu/ei/Xm ==================
    #pragma unroll
    for (int lr = 0; lr < 8; ++lr) {
        const int rl = wid * 8 + lr;    // local row 0..63
        const int r  = __builtin_amdgcn_readfirstlane(m0 + rl);
        const int u   = __builtin_amdgcn_readfirstlane(user[r]);
        const int itm = __builtin_amdgcn_readfirstlane(item[r]);
        float2 a = *(const float2*)(eu + (size_t)u   * 128 + 2 * lane);
        float2 b = *(const float2*)(ei + (size_t)itm * 128 + 2 * lane);
        ushort2 pa; pa.x = f2bf(a.x); pa.y = f2bf(a.y);
        ushort2 pb; pb.x = f2bf(b.x); pb.y = f2bf(b.y);
        *(ushort2*)(Xs + rl * 456 + 2 * lane)       = pa;
        *(ushort2*)(Xs + rl * 456 + 128 + 2 * lane) = pb;
        if (lane < 24)                  // 24 x 16B = 192 ush = the 3 means
            *(bfrag8*)(Xs + rl * 456 + 256 + lane * 8) =
                *(const bfrag8*)(Xm + (size_t)(m0 + rl) * 192 + lane * 8);
    }
    __syncthreads();                    // Xs complete; g1b0 resident

    // ================= GEMM1: [64,448] @ W1 -> H1 [64,256] ==================
    facc4 acc1[4][2];
    #pragma unroll
    for (int mt = 0; mt < 4; ++mt)
        #pragma unroll
        for (int nt = 0; nt < 2; ++nt)
            acc1[mt][nt] = (facc4){0.f, 0.f, 0.f, 0.f};

    #pragma unroll
    for (int kp = 0; kp < 7; ++kp) {            // K = 448 = 7 * (2*32)
        const int ksA = 2 * kp, ksB = 2 * kp + 1;
        #pragma unroll
        for (int nt = 0; nt < 2; ++nt)          // prefetch ksB
            g1b1[nt] = *(const bfrag8*)(WT1 + (size_t)(wid * 32 + nt * 16 + lm) * 448
                                            + ksB * 32 + quad * 8);
        bfrag8 af[4];
        #pragma unroll
        for (int mt = 0; mt < 4; ++mt)
            af[mt] = *(const bfrag8*)(Xs + (mt * 16 + lm) * 456 + ksA * 32 + quad * 8);
        #pragma unroll
        for (int mt = 0; mt < 4; ++mt)
            #pragma unroll
            for (int nt = 0; nt < 2; ++nt)
                acc1[mt][nt] = __builtin_amdgcn_mfma_f32_16x16x32_bf16(
                    af[mt], g1b0[nt], acc1[mt][nt], 0, 0, 0);
        if (kp < 6) {
            #pragma unroll
            for (int nt = 0; nt < 2; ++nt)      // prefetch next pair's ksA
                g1b0[nt] = *(const bfrag8*)(WT1 + (size_t)(wid * 32 + nt * 16 + lm) * 448
                                                + (ksB + 1) * 32 + quad * 8);
        }
        #pragma unroll
        for (int mt = 0; mt < 4; ++mt)
            af[mt] = *(const bfrag8*)(Xs + (mt * 16 + lm) * 456 + ksB * 32 + quad * 8);
        #pragma unroll
        for (int mt = 0; mt < 4; ++mt)
            #pragma unroll
            for (int nt = 0; nt < 2; ++nt)
                acc1[mt][nt] = __builtin_amdgcn_mfma_f32_16x16x32_bf16(
                    af[mt], g1b1[nt], acc1[mt][nt], 0, 0, 0);
    }

    // ---- early issue: GEMM2 B (ks=0) ----
    const int colw = wid * 16 + lm;             // this wave's col in GEMM2/H2
    bfrag8 g2b0 = *(const bfrag8*)(WT2 + (size_t)colw * 256 + quad * 8);
    bfrag8 g2b1;

    __syncthreads();                            // all Xs reads done

    // epilogue 1 -> H1s (C/D: col=lane&15 base, row=quad*4+reg)
    #pragma unroll
    for (int nt = 0; nt < 2; ++nt) {
        const int col = wid * 32 + nt * 16 + lm;
        const float bias = b1[col];
        #pragma unroll
        for (int mt = 0; mt < 4; ++mt)
            #pragma unroll
            for (int i = 0; i < 4; ++i) {
                const int row = mt * 16 + quad * 4 + i;
                H1s[row * 264 + col] = f2bf(fmaxf(acc1[mt][nt][i] + bias, 0.f));
            }
    }
    __syncthreads();

    // ================= GEMM2: [64,256] @ W2 -> H2 [64,128] ==================
    facc4 acc2[4];
    #pragma unroll
    for (int mt = 0; mt < 4; ++mt) acc2[mt] = (facc4){0.f, 0.f, 0.f, 0.f};

    #pragma unroll
    for (int kp = 0; kp < 4; ++kp) {            // K = 256 = 4 * (2*32)
        const int ksA = 2 * kp, ksB = 2 * kp + 1;
        g2b1 = *(const bfrag8*)(WT2 + (size_t)colw * 256 + ksB * 32 + quad * 8);
        bfrag8 af[4];
        #pragma unroll
        for (int mt = 0; mt < 4; ++mt)
            af[mt] = *(const bfrag8*)(H1s + (mt * 16 + lm) * 264 + ksA * 32 + quad * 8);
        #pragma unroll
        for (int mt = 0; mt < 4; ++mt)
            acc2[mt] = __builtin_amdgcn_mfma_f32_16x16x32_bf16(af[mt], g2b0, acc2[mt], 0, 0, 0);
        if (kp < 3)
            g2b0 = *(const bfrag8*)(WT2 + (size_t)colw * 256 + (ksB + 1) * 32 + quad * 8);
        #pragma unroll
        for (int mt = 0; mt < 4; ++mt)
            af[mt] = *(const bfrag8*)(H1s + (mt * 16 + lm) * 264 + ksB * 32 + quad * 8);
        #pragma unroll
        for (int mt = 0; mt < 4; ++mt)
            acc2[mt] = __builtin_amdgcn_mfma_f32_16x16x32_bf16(af[mt], g2b1, acc2[mt], 0, 0, 0);
    }

    // ---- early issue: GEMM3 B (all 4 ks) ----
    const int w3   = wid & 3;
    const int mgrp = wid >> 2;
    const int col3 = w3 * 16 + lm;
    bfrag8 g3b[4];
    #pragma unroll
    for (int ks = 0; ks < 4; ++ks)
        g3b[ks] = *(const bfrag8*)(WT3 + (size_t)col3 * 128 + ks * 32 + quad * 8);

    // epilogue 2 -> H2s (disjoint from H1s reads; barrier only after)
    {
        const float bias = b2[colw];
        #pragma unroll
        for (int mt = 0; mt < 4; ++mt)
            #pragma unroll
            for (int i = 0; i < 4; ++i) {
                const int row = mt * 16 + quad * 4 + i;
                H2s[row * 136 + colw] = f2bf(fmaxf(acc2[mt][i] + bias, 0.f));
            }
    }
    __syncthreads();

    // ========= GEMM3: [64,128] @ W3 -> relu -> dot Wp, fused reduce =========
    {
        facc4 acc3[2];
        #pragma unroll
        for (int mtl = 0; mtl < 2; ++mtl) acc3[mtl] = (facc4){0.f, 0.f, 0.f, 0.f};

        #pragma unroll
        for (int ks = 0; ks < 4; ++ks) {        // K = 128 = 4 * 32
            bfrag8 af[2];
            #pragma unroll
            for (int mtl = 0; mtl < 2; ++mtl)
                af[mtl] = *(const bfrag8*)(H2s + (mgrp * 32 + mtl * 16 + lm) * 136
                                               + ks * 32 + quad * 8);
            #pragma unroll
            for (int mtl = 0; mtl < 2; ++mtl)
                acc3[mtl] = __builtin_amdgcn_mfma_f32_16x16x32_bf16(
                    af[mtl], g3b[ks], acc3[mtl], 0, 0, 0);
        }
        const float bias = b3[col3];
        const float wpv  = Wp[col3];
        #pragma unroll
        for (int mtl = 0; mtl < 2; ++mtl)
            #pragma unroll
            for (int i = 0; i < 4; ++i) {
                float p = fmaxf(acc3[mtl][i] + bias, 0.f) * wpv;
                p += __shfl_xor(p, 1);
                p += __shfl_xor(p, 2);
                p += __shfl_xor(p, 4);
                p += __shfl_xor(p, 8);          // sum over the 16 cols (lm)
                if (lm == 0) tmp[mgrp * 32 + mtl * 16 + quad * 4 + i][w3] = p;
            }
    }
    __syncthreads();

    if (tid < 64)
        out[m0 + tid] = tmp[tid][0] + tmp[tid][1] + tmp[tid][2] + tmp[tid][3] + bp[0];
}

// ---------------------------------------------------------------------------
extern "C" void kernel_launch(void* const* d_in, const int* in_sizes, int n_in,
                              void* d_out, int out_size, void* d_ws, size_t ws_size,
                              hipStream_t stream) {
    (void)in_sizes; (void)n_in; (void)out_size; (void)ws_size;

    const int*   user = (const int*)d_in[0];
    const int*   item = (const int*)d_in[1];
    const int*   pk   = (const int*)d_in[2];
    const int*   tk   = (const int*)d_in[3];
    const int*   ik   = (const int*)d_in[4];
    const int*   vp   = (const int*)d_in[5];
    const int*   vt   = (const int*)d_in[6];
    const int*   vi   = (const int*)d_in[7];
    const float* eu   = (const float*)d_in[8];
    const float* ei   = (const float*)d_in[9];
    const float* ek   = (const float*)d_in[10];
    const float* W1   = (const float*)d_in[11];
    const float* b1   = (const float*)d_in[12];
    const float* W2   = (const float*)d_in[13];
    const float* b2   = (const float*)d_in[14];
    const float* W3   = (const float*)d_in[15];
    const float* b3   = (const float*)d_in[16];
    const float* Wp   = (const float*)d_in[17];
    const float* bp   = (const float*)d_in[18];
    float* out = (float*)d_out;

    // ws layout (~26 MB):
    //   WT1 114688 ush | WT2 32768 | WT3 8192 | ekb 320064 ush | Xm 65536x192 ush
    unsigned short* WT1 = (unsigned short*)d_ws;
    unsigned short* WT2 = WT1 + 114688;
    unsigned short* WT3 = WT2 + 32768;
    unsigned short* ekb = WT3 + 8192;
    unsigned short* Xm  = ekb + 320064;   // 16B-aligned (475712 ush from base)

    prepack<<<1859, 256, 0, stream>>>(W1, W2, W3, ek, WT1, WT2, WT3, ekb);

    kdmlp_gather<<<2048, 256, 0, stream>>>(pk, tk, ik, vp, vt, vi, ekb, Xm);

    kdmlp_mlp<<<1024, 512, 0, stream>>>(
        user, item, eu, ei, Xm, WT1, WT2, WT3, b1, b2, b3, Wp, bp, out);
}